// Round 2
// baseline (63.507 us; speedup 1.0000x reference)
//
#include <hip/hip_runtime.h>

#define NN 32
#define MM 128
#define EE 256
#define DD 128

typedef __attribute__((ext_vector_type(8))) short short8;
typedef __attribute__((ext_vector_type(4))) float f32x4;

union U16x8 { uint4 u; short8 s; };

static __device__ __forceinline__ unsigned short f2bf(float f) {
  union { float f; unsigned u; } v; v.f = f;
  unsigned r = v.u + 0x7FFFu + ((v.u >> 16) & 1u);   // RNE
  return (unsigned short)(r >> 16);
}

// ---------------- kernel 1: L = einsum('nd,jd->nj') per i, softmax -> P1 (bf16); P0 = softmax(bkk) ----
__global__ __launch_bounds__(128, 1)
void k_prep(const float* __restrict__ X, const float* __restrict__ Wkk,
            const float* __restrict__ bkk,
            unsigned short* __restrict__ P1g, unsigned short* __restrict__ P0g) {
  const int i  = blockIdx.x;
  const int ty = threadIdx.x >> 6;       // wave = row-frag (n 16-block)
  const int l  = threadIdx.x & 63;
  const int lr = l & 15, lg = l >> 4;

  // A frags: rows n = ty*16+lr, k = d
  short8 a[4];
  {
    const int n = ty * 16 + lr;
    const float* xp = X + (n * MM + i) * DD + lg * 8;
#pragma unroll
    for (int k = 0; k < 4; ++k) {
      float4 v0 = *(const float4*)(xp + k * 32);
      float4 v1 = *(const float4*)(xp + k * 32 + 4);
      short8 s;
      s[0]=(short)f2bf(v0.x); s[1]=(short)f2bf(v0.y); s[2]=(short)f2bf(v0.z); s[3]=(short)f2bf(v0.w);
      s[4]=(short)f2bf(v1.x); s[5]=(short)f2bf(v1.y); s[6]=(short)f2bf(v1.z); s[7]=(short)f2bf(v1.w);
      a[k] = s;
    }
  }
  f32x4 acc[8];
#pragma unroll
  for (int cf = 0; cf < 8; ++cf) acc[cf] = (f32x4){0.f, 0.f, 0.f, 0.f};

#pragma unroll
  for (int k = 0; k < 4; ++k) {
#pragma unroll
    for (int cf = 0; cf < 8; ++cf) {
      const int j = cf * 16 + lr;
      const float* wp = Wkk + (i * MM + j) * DD + k * 32 + lg * 8;
      float4 v0 = *(const float4*)(wp);
      float4 v1 = *(const float4*)(wp + 4);
      short8 b;
      b[0]=(short)f2bf(v0.x); b[1]=(short)f2bf(v0.y); b[2]=(short)f2bf(v0.z); b[3]=(short)f2bf(v0.w);
      b[4]=(short)f2bf(v1.x); b[5]=(short)f2bf(v1.y); b[6]=(short)f2bf(v1.z); b[7]=(short)f2bf(v1.w);
      acc[cf] = __builtin_amdgcn_mfma_f32_16x16x32_bf16(a[k], b, acc[cf], 0, 0, 0);
    }
  }

  float bk[8];
#pragma unroll
  for (int cf = 0; cf < 8; ++cf) bk[cf] = bkk[i * MM + cf * 16 + lr];

#pragma unroll
  for (int r = 0; r < 4; ++r) {
    float v[8], m = -1e30f;
#pragma unroll
    for (int cf = 0; cf < 8; ++cf) { v[cf] = acc[cf][r] + bk[cf]; m = fmaxf(m, v[cf]); }
#pragma unroll
    for (int s = 1; s < 16; s <<= 1) m = fmaxf(m, __shfl_xor(m, s, 64));
    float sum = 0.f;
#pragma unroll
    for (int cf = 0; cf < 8; ++cf) { v[cf] = __expf(v[cf] - m); sum += v[cf]; }
#pragma unroll
    for (int s = 1; s < 16; s <<= 1) sum += __shfl_xor(sum, s, 64);
    const float inv = 1.f / sum;
    const int n = ty * 16 + lg * 4 + r;
    unsigned short* dst = P1g + (n * MM + i) * MM;
#pragma unroll
    for (int cf = 0; cf < 8; ++cf) dst[cf * 16 + lr] = f2bf(v[cf] * inv);
  }

  if (ty == 0) {  // P0 row i
    float v0 = bkk[i * MM + l], v1 = bkk[i * MM + 64 + l];
    float m = fmaxf(v0, v1);
#pragma unroll
    for (int s = 1; s < 64; s <<= 1) m = fmaxf(m, __shfl_xor(m, s, 64));
    v0 = __expf(v0 - m); v1 = __expf(v1 - m);
    float sum = v0 + v1;
#pragma unroll
    for (int s = 1; s < 64; s <<= 1) sum += __shfl_xor(sum, s, 64);
    const float inv = 1.f / sum;
    P0g[i * MM + l]      = f2bf(v0 * inv);
    P0g[i * MM + 64 + l] = f2bf(v1 * inv);
  }
}

// ---------------- kernel 1b: XT[n][d][j] = bf16(X[n][j][d]) ----------------
__global__ __launch_bounds__(256, 1)
void k_xt(const float* __restrict__ X, unsigned short* __restrict__ XTg) {
  __shared__ float xs[128][129];
  const int n = blockIdx.x, t = threadIdx.x;
#pragma unroll
  for (int it = 0; it < 16; ++it) {
    int idx = it * 256 + t;           // 0..4095 float4 tiles
    int j = idx >> 5, dq = idx & 31;
    float4 v = *(const float4*)(X + (n * MM + j) * DD + dq * 4);
    xs[j][dq * 4 + 0] = v.x; xs[j][dq * 4 + 1] = v.y;
    xs[j][dq * 4 + 2] = v.z; xs[j][dq * 4 + 3] = v.w;
  }
  __syncthreads();
  const int d = t >> 1, jh = t & 1;
  unsigned* dst = (unsigned*)XTg + (n * DD + d) * (MM / 2) + jh * 32;
#pragma unroll
  for (int jj = 0; jj < 32; ++jj) {
    int j = jh * 64 + jj * 2;
    unsigned u0 = f2bf(xs[j][d]), u1 = f2bf(xs[j + 1][d]);
    dst[jj] = u0 | (u1 << 16);
  }
}

// ---------------- kernel 2: main. 256 blocks (n=bid&31, eg=bid>>5), 32 e's per block ---------------
__global__ __launch_bounds__(256, 1)
void k_main(const unsigned short* __restrict__ P0g, const unsigned short* __restrict__ P1g,
            const unsigned short* __restrict__ XTg, const float* __restrict__ inc,
            const float* __restrict__ w1, const float* __restrict__ b1p,
            float* __restrict__ out) {
  __shared__ alignas(128) unsigned short Plds[2][128][128];  // [0]=P0, [1]=P1[n], XOR-swizzled
  __shared__ alignas(128) unsigned short XTlds[128][128];    // XOR-swizzled
  __shared__ unsigned int bitm[32][4];                       // inc bitmap per local e
  __shared__ alignas(16) unsigned short mrow[32][128];       // 0xFFFF / 0 column masks

  const int n  = blockIdx.x & 31;
  const int eg = blockIdx.x >> 5;        // 0..7, 32 e's each
  const int t  = threadIdx.x;
  const int w  = t >> 6, l = t & 63, lr = l & 15, lg = l >> 4;

  { // stage P0, P1[n], XT[n] with xor-swizzle ^((row&7)<<4); row = byte>>8 = idx>>4
    char* d0 = (char*)&Plds[0][0][0];
    char* d1 = (char*)&Plds[1][0][0];
    char* d2 = (char*)&XTlds[0][0];
    const uint4* s0 = (const uint4*)P0g;
    const uint4* s1 = (const uint4*)(P1g + n * MM * MM);
    const uint4* s2 = (const uint4*)(XTg + n * DD * MM);
#pragma unroll
    for (int it = 0; it < 8; ++it) {
      int idx = it * 256 + t;                       // 0..2047 16B chunks
      int off = (idx * 16) ^ (((idx >> 4) & 7) << 4);
      *(uint4*)(d0 + off) = s0[idx];
      *(uint4*)(d1 + off) = s1[idx];
      *(uint4*)(d2 + off) = s2[idx];
    }
  }
  if (t < 128) {  // incidence bitmap for this block's 32 e's
    int el = t >> 2, wd = t & 3;
    int e = eg * 32 + el;
    unsigned bm = 0;
    for (int b = 0; b < 32; ++b) {
      float v = inc[(n * MM + wd * 32 + b) * EE + e];
      if (v != 0.f) bm |= (1u << b);
    }
    bitm[el][wd] = bm;
  }
  float wv[8];
#pragma unroll
  for (int cf = 0; cf < 8; ++cf) wv[cf] = w1[cf * 16 + lr];
  const float b1v = b1p[0];
  __syncthreads();

  { // expand bitmap -> u16 AND-masks
    int el = t >> 3, j0 = (t & 7) * 16;
    unsigned wd = bitm[el][j0 >> 5];
    int sh = j0 & 31;
    unsigned short* mp = &mrow[el][j0];
#pragma unroll
    for (int b = 0; b < 16; ++b) mp[b] = ((wd >> (sh + b)) & 1u) ? 0xFFFFu : 0u;
  }
  __syncthreads();

  // B fragments (X[n], e-invariant) -> registers for the whole block
  short8 B[8][4];
  {
    const char* base = (const char*)&XTlds[0][0];
#pragma unroll
    for (int cf = 0; cf < 8; ++cf) {
      int drow = cf * 16 + lr;
#pragma unroll
      for (int k = 0; k < 4; ++k) {
        int off = (drow * 256 + k * 64 + lg * 16) ^ ((drow & 7) << 4);
        U16x8 tmp; tmp.u = *(const uint4*)(base + off);
        B[cf][k] = tmp.s;
      }
    }
  }

  const char* pbase = (const char*)&Plds[0][0][0];
  float* outp = out + (n * EE + eg * 32) * MM;

#pragma unroll 1
  for (int el = 0; el < 32; ++el) {
    const unsigned selw = bitm[el][w];     // bits for rows w*32..w*32+31
    f32x4 acc[2][8];
#pragma unroll
    for (int rf = 0; rf < 2; ++rf)
#pragma unroll
      for (int cf = 0; cf < 8; ++cf) acc[rf][cf] = (f32x4){0.f, 0.f, 0.f, 0.f};

#pragma unroll
    for (int k = 0; k < 4; ++k) {
      uint4 mm = *(const uint4*)((const char*)&mrow[el][0] + k * 64 + lg * 16);
#pragma unroll
      for (int rf = 0; rf < 2; ++rf) {
        const int row = w * 32 + rf * 16 + lr;
        const unsigned sel = (selw >> (rf * 16 + lr)) & 1u;
        const int off = (row * 256 + k * 64 + lg * 16) ^ ((row & 7) << 4);
        U16x8 av; av.u = *(const uint4*)(pbase + sel * 32768u + off);
        av.u.x &= mm.x; av.u.y &= mm.y; av.u.z &= mm.z; av.u.w &= mm.w;
#pragma unroll
        for (int cf = 0; cf < 8; ++cf)
          acc[rf][cf] = __builtin_amdgcn_mfma_f32_16x16x32_bf16(av.s, B[cf][k], acc[rf][cf], 0, 0, 0);
      }
    }
    // epilogue: relu, *w1, reduce over 128 cols, store
#pragma unroll
    for (int rf = 0; rf < 2; ++rf) {
      float p[4];
#pragma unroll
      for (int r = 0; r < 4; ++r) {
        float sum = 0.f;
#pragma unroll
        for (int cf = 0; cf < 8; ++cf) sum += fmaxf(acc[rf][cf][r], 0.f) * wv[cf];
        p[r] = sum;
      }
#pragma unroll
      for (int s = 1; s < 16; s <<= 1) {
#pragma unroll
        for (int r = 0; r < 4; ++r) p[r] += __shfl_xor(p[r], s, 64);
      }
      if (lr == 0) {
        float* op = outp + el * MM + w * 32 + rf * 16 + lg * 4;
#pragma unroll
        for (int r = 0; r < 4; ++r) op[r] = p[r] + b1v;
      }
    }
  }
}

extern "C" void kernel_launch(void* const* d_in, const int* in_sizes, int n_in,
                              void* d_out, int out_size, void* d_ws, size_t ws_size,
                              hipStream_t stream) {
  const float* X   = (const float*)d_in[0];
  const float* inc = (const float*)d_in[1];
  const float* Wkk = (const float*)d_in[2];
  const float* bkk = (const float*)d_in[3];
  const float* w1  = (const float*)d_in[4];
  const float* b1  = (const float*)d_in[5];
  float* out = (float*)d_out;

  unsigned short* P1g = (unsigned short*)d_ws;          // 32*128*128
  unsigned short* XTg = P1g + NN * MM * DD;             // 32*128*128
  unsigned short* P0g = XTg + NN * MM * DD;             // 128*128

  hipLaunchKernelGGL(k_prep, dim3(128), dim3(128), 0, stream, X, Wkk, bkk, P1g, P0g);
  hipLaunchKernelGGL(k_xt,   dim3(32),  dim3(256), 0, stream, X, XTg);
  hipLaunchKernelGGL(k_main, dim3(256), dim3(256), 0, stream, P0g, P1g, XTg, inc, w1, b1, out);
}

// Round 3
// 57.866 us; speedup vs baseline: 1.0975x; 1.0975x over previous
//
#include <hip/hip_runtime.h>

#define NN 32
#define MM 128
#define EE 256
#define DD 128
#define ELB 16   // e's per k_main block

typedef __attribute__((ext_vector_type(8))) short short8;
typedef __attribute__((ext_vector_type(4))) float f32x4;

union U16x8 { uint4 u; short8 s; };

static __device__ __forceinline__ unsigned short f2bf(float f) {
  union { float f; unsigned u; } v; v.f = f;
  unsigned r = v.u + 0x7FFFu + ((v.u >> 16) & 1u);   // RNE
  return (unsigned short)(r >> 16);
}

// ---------------- kernel 1: L = einsum('nd,jd->nj') per i, softmax -> P1 (bf16); P0 = softmax(bkk) ----
__global__ __launch_bounds__(128, 1)
void k_prep(const float* __restrict__ X, const float* __restrict__ Wkk,
            const float* __restrict__ bkk,
            unsigned short* __restrict__ P1g, unsigned short* __restrict__ P0g) {
  const int i  = blockIdx.x;
  const int ty = threadIdx.x >> 6;       // wave = row-frag (n 16-block)
  const int l  = threadIdx.x & 63;
  const int lr = l & 15, lg = l >> 4;

  short8 a[4];
  {
    const int n = ty * 16 + lr;
    const float* xp = X + (n * MM + i) * DD + lg * 8;
#pragma unroll
    for (int k = 0; k < 4; ++k) {
      float4 v0 = *(const float4*)(xp + k * 32);
      float4 v1 = *(const float4*)(xp + k * 32 + 4);
      short8 s;
      s[0]=(short)f2bf(v0.x); s[1]=(short)f2bf(v0.y); s[2]=(short)f2bf(v0.z); s[3]=(short)f2bf(v0.w);
      s[4]=(short)f2bf(v1.x); s[5]=(short)f2bf(v1.y); s[6]=(short)f2bf(v1.z); s[7]=(short)f2bf(v1.w);
      a[k] = s;
    }
  }
  f32x4 acc[8];
#pragma unroll
  for (int cf = 0; cf < 8; ++cf) acc[cf] = (f32x4){0.f, 0.f, 0.f, 0.f};

#pragma unroll
  for (int k = 0; k < 4; ++k) {
#pragma unroll
    for (int cf = 0; cf < 8; ++cf) {
      const int j = cf * 16 + lr;
      const float* wp = Wkk + (i * MM + j) * DD + k * 32 + lg * 8;
      float4 v0 = *(const float4*)(wp);
      float4 v1 = *(const float4*)(wp + 4);
      short8 b;
      b[0]=(short)f2bf(v0.x); b[1]=(short)f2bf(v0.y); b[2]=(short)f2bf(v0.z); b[3]=(short)f2bf(v0.w);
      b[4]=(short)f2bf(v1.x); b[5]=(short)f2bf(v1.y); b[6]=(short)f2bf(v1.z); b[7]=(short)f2bf(v1.w);
      acc[cf] = __builtin_amdgcn_mfma_f32_16x16x32_bf16(a[k], b, acc[cf], 0, 0, 0);
    }
  }

  float bk[8];
#pragma unroll
  for (int cf = 0; cf < 8; ++cf) bk[cf] = bkk[i * MM + cf * 16 + lr];

#pragma unroll
  for (int r = 0; r < 4; ++r) {
    float v[8], m = -1e30f;
#pragma unroll
    for (int cf = 0; cf < 8; ++cf) { v[cf] = acc[cf][r] + bk[cf]; m = fmaxf(m, v[cf]); }
#pragma unroll
    for (int s = 1; s < 16; s <<= 1) m = fmaxf(m, __shfl_xor(m, s, 64));
    float sum = 0.f;
#pragma unroll
    for (int cf = 0; cf < 8; ++cf) { v[cf] = __expf(v[cf] - m); sum += v[cf]; }
#pragma unroll
    for (int s = 1; s < 16; s <<= 1) sum += __shfl_xor(sum, s, 64);
    const float inv = 1.f / sum;
    const int n = ty * 16 + lg * 4 + r;
    unsigned short* dst = P1g + (n * MM + i) * MM;
#pragma unroll
    for (int cf = 0; cf < 8; ++cf) dst[cf * 16 + lr] = f2bf(v[cf] * inv);
  }

  if (ty == 0) {  // P0 row i
    float v0 = bkk[i * MM + l], v1 = bkk[i * MM + 64 + l];
    float m = fmaxf(v0, v1);
#pragma unroll
    for (int s = 1; s < 64; s <<= 1) m = fmaxf(m, __shfl_xor(m, s, 64));
    v0 = __expf(v0 - m); v1 = __expf(v1 - m);
    float sum = v0 + v1;
#pragma unroll
    for (int s = 1; s < 64; s <<= 1) sum += __shfl_xor(sum, s, 64);
    const float inv = 1.f / sum;
    P0g[i * MM + l]      = f2bf(v0 * inv);
    P0g[i * MM + 64 + l] = f2bf(v1 * inv);
  }
}

// ---------------- kernel 1b: XT[n][d][j] = bf16(X[n][j][d]) ----------------
__global__ __launch_bounds__(256, 1)
void k_xt(const float* __restrict__ X, unsigned short* __restrict__ XTg) {
  __shared__ float xs[128][129];
  const int n = blockIdx.x, t = threadIdx.x;
#pragma unroll
  for (int it = 0; it < 16; ++it) {
    int idx = it * 256 + t;           // 0..4095 float4 tiles
    int j = idx >> 5, dq = idx & 31;
    float4 v = *(const float4*)(X + (n * MM + j) * DD + dq * 4);
    xs[j][dq * 4 + 0] = v.x; xs[j][dq * 4 + 1] = v.y;
    xs[j][dq * 4 + 2] = v.z; xs[j][dq * 4 + 3] = v.w;
  }
  __syncthreads();
  const int d = t >> 1, jh = t & 1;
  unsigned* dst = (unsigned*)XTg + (n * DD + d) * (MM / 2) + jh * 32;
#pragma unroll
  for (int jj = 0; jj < 32; ++jj) {
    int j = jh * 64 + jj * 2;
    unsigned u0 = f2bf(xs[j][d]), u1 = f2bf(xs[j + 1][d]);
    dst[jj] = u0 | (u1 << 16);
  }
}

// ---------------- kernel 2: main. 512 blocks (n=bid&31, eg=bid>>5 in 0..15), 16 e's per block -------
__global__ __launch_bounds__(256, 2)
void k_main(const unsigned short* __restrict__ P0g, const unsigned short* __restrict__ P1g,
            const unsigned short* __restrict__ XTg, const float* __restrict__ inc,
            const float* __restrict__ w1, const float* __restrict__ b1p,
            float* __restrict__ out) {
  __shared__ alignas(128) unsigned short Plds[2][128][128];  // [0]=P0, [1]=P1[n], XOR-swizzled (64KB)
  __shared__ unsigned int bitm[ELB][4];                      // inc bitmap per local e
  __shared__ alignas(16) unsigned short mrow[ELB][128];      // 0xFFFF / 0 column masks (4KB)

  const int n  = blockIdx.x & 31;
  const int eg = blockIdx.x >> 5;        // 0..15, ELB e's each
  const int t  = threadIdx.x;
  const int w  = t >> 6, l = t & 63, lr = l & 15, lg = l >> 4;

  { // stage P0, P1[n] with xor-swizzle ^((row&7)<<4); row = byte>>8 = idx>>4
    char* d0 = (char*)&Plds[0][0][0];
    char* d1 = (char*)&Plds[1][0][0];
    const uint4* s0 = (const uint4*)P0g;
    const uint4* s1 = (const uint4*)(P1g + n * MM * MM);
#pragma unroll
    for (int it = 0; it < 8; ++it) {
      int idx = it * 256 + t;                       // 0..2047 16B chunks
      int off = (idx * 16) ^ (((idx >> 4) & 7) << 4);
      *(uint4*)(d0 + off) = s0[idx];
      *(uint4*)(d1 + off) = s1[idx];
    }
  }
  if (t < ELB * 4) {  // incidence bitmap for this block's e's
    int el = t >> 2, wd = t & 3;
    int e = eg * ELB + el;
    unsigned bm = 0;
    for (int b = 0; b < 32; ++b) {
      float v = inc[(n * MM + wd * 32 + b) * EE + e];
      if (v != 0.f) bm |= (1u << b);
    }
    bitm[el][wd] = bm;
  }

  // B fragments (X[n], e-invariant) straight from global XT -> registers
  short8 B[8][4];
  {
    const unsigned short* xb = XTg + n * DD * MM;
#pragma unroll
    for (int cf = 0; cf < 8; ++cf) {
      int drow = cf * 16 + lr;
#pragma unroll
      for (int k = 0; k < 4; ++k) {
        U16x8 tmp; tmp.u = *(const uint4*)(xb + drow * MM + k * 32 + lg * 8);
        B[cf][k] = tmp.s;
      }
    }
  }
  float wv[8];
#pragma unroll
  for (int cf = 0; cf < 8; ++cf) wv[cf] = w1[cf * 16 + lr];
  const float b1v = b1p[0];
  __syncthreads();

  if (t < ELB * 8) { // expand bitmap -> u16 AND-masks
    int el = t >> 3, j0 = (t & 7) * 16;
    unsigned wd = bitm[el][j0 >> 5];
    int sh = j0 & 31;
    unsigned short* mp = &mrow[el][j0];
#pragma unroll
    for (int b = 0; b < 16; ++b) mp[b] = ((wd >> (sh + b)) & 1u) ? 0xFFFFu : 0u;
  }
  __syncthreads();

  const char* pbase = (const char*)&Plds[0][0][0];
  float* outp = out + (n * EE + eg * ELB) * MM;

#pragma unroll 1
  for (int el = 0; el < ELB; ++el) {
    const unsigned selw = bitm[el][w];     // bits for rows w*32..w*32+31
    f32x4 acc[2][8];
#pragma unroll
    for (int rf = 0; rf < 2; ++rf)
#pragma unroll
      for (int cf = 0; cf < 8; ++cf) acc[rf][cf] = (f32x4){0.f, 0.f, 0.f, 0.f};

#pragma unroll
    for (int k = 0; k < 4; ++k) {
      uint4 mm = *(const uint4*)((const char*)&mrow[el][0] + k * 64 + lg * 16);
#pragma unroll
      for (int rf = 0; rf < 2; ++rf) {
        const int row = w * 32 + rf * 16 + lr;
        const unsigned sel = (selw >> (rf * 16 + lr)) & 1u;
        const int off = (row * 256 + k * 64 + lg * 16) ^ ((row & 7) << 4);
        U16x8 av; av.u = *(const uint4*)(pbase + sel * 32768u + off);
        av.u.x &= mm.x; av.u.y &= mm.y; av.u.z &= mm.z; av.u.w &= mm.w;
#pragma unroll
        for (int cf = 0; cf < 8; ++cf)
          acc[rf][cf] = __builtin_amdgcn_mfma_f32_16x16x32_bf16(av.s, B[cf][k], acc[rf][cf], 0, 0, 0);
      }
    }
    // epilogue: relu, *w1, reduce over 128 cols (8 parallel shuffle chains), store
    float p[2][4];
#pragma unroll
    for (int rf = 0; rf < 2; ++rf)
#pragma unroll
      for (int r = 0; r < 4; ++r) {
        float sum = 0.f;
#pragma unroll
        for (int cf = 0; cf < 8; ++cf) sum += fmaxf(acc[rf][cf][r], 0.f) * wv[cf];
        p[rf][r] = sum;
      }
#pragma unroll
    for (int s = 1; s < 16; s <<= 1)
#pragma unroll
      for (int rf = 0; rf < 2; ++rf)
#pragma unroll
        for (int r = 0; r < 4; ++r) p[rf][r] += __shfl_xor(p[rf][r], s, 64);
    if (lr == 0) {
#pragma unroll
      for (int rf = 0; rf < 2; ++rf) {
        float* op = outp + el * MM + w * 32 + rf * 16 + lg * 4;
#pragma unroll
        for (int r = 0; r < 4; ++r) op[r] = p[rf][r] + b1v;
      }
    }
  }
}

extern "C" void kernel_launch(void* const* d_in, const int* in_sizes, int n_in,
                              void* d_out, int out_size, void* d_ws, size_t ws_size,
                              hipStream_t stream) {
  const float* X   = (const float*)d_in[0];
  const float* inc = (const float*)d_in[1];
  const float* Wkk = (const float*)d_in[2];
  const float* bkk = (const float*)d_in[3];
  const float* w1  = (const float*)d_in[4];
  const float* b1  = (const float*)d_in[5];
  float* out = (float*)d_out;

  unsigned short* P1g = (unsigned short*)d_ws;          // 32*128*128
  unsigned short* XTg = P1g + NN * MM * DD;             // 32*128*128
  unsigned short* P0g = XTg + NN * MM * DD;             // 128*128

  hipLaunchKernelGGL(k_prep, dim3(128), dim3(128), 0, stream, X, Wkk, bkk, P1g, P0g);
  hipLaunchKernelGGL(k_xt,   dim3(32),  dim3(256), 0, stream, X, XTg);
  hipLaunchKernelGGL(k_main, dim3(512), dim3(256), 0, stream, P0g, P1g, XTg, inc, w1, b1, out);
}